// Round 4
// baseline (137.821 us; speedup 1.0000x reference)
//
#include <hip/hip_runtime.h>

#define BB 8
#define LL 1024
#define DD 512
#define HDIM 4096
#define EPS_LN 1e-5f
#define NBLK 256
#define NT 1024
#define NW 128                    // weight-role blocks; X-role = NBLK-NW = 128
#define POISON_I ((int)0xAAAAAAAAu)

// R13: producer/consumer ROLE SPLIT — phases run concurrently, not serially.
//
// Evidence trail:
//  R10: removing ALL sync (3-kernel split) was neutral  -> sync ~free.
//  R11: 48-float reg prefetch spilled (WRITE_SIZE 37MB) -> no long-lived reg arrays.
//  R12: 32 waves/CU regressed 31->40us; fills hit 6.3TB/s at 8.7% occupancy
//       -> wave count is not the limiter.
//  => The cost is the SERIAL phase structure: 3 whole-GPU HBM drain/ramp
//     cycles + 2 all-block skew waits over a ~10us streaming roofline.
//
// R13 structure: 256 blocks x 1024 thr, ONE block per CU (129KB LDS forces
// it; 256 blocks <= 256 CUs => all resident, deadlock-impossible).
//  W-blocks (bi<128): stage own 32-col wv chunk (64KB) + fcw chunk (64KB)
//    into LDS at t=0 — overlaps the X-side x-read — spin for xs, then
//    T = xs@wv + 1024*bv and u-partials from LDS, atomicAdd u, arrive.
//    Weights fetched from HBM exactly once (no L2-dedup assumption).
//  X-blocks (bi>=128): 64 rows each: reduce -> atomicAdd xs -> arrive ->
//    spin for u -> LN with x re-read from L3 (48MB working set << 256MB).
//
// Sync/poison: IDENTICAL proven R2-R9 pattern. xs/u written ONLY via
// device-scope atomicAdd (poison 0xAAAAAAAA == -3.03e-13f ~ 0); arrival =
// vmcnt(0) drain -> relaxed agent-scope add; readers first-touch lines only
// after observing count==POISON_I+128 (control dep via __syncthreads).
//
// ws layout unchanged: xs 16KB @0, bar @16K (xs_cnt=bar[0], u_cnt=bar[64]),
// u 16KB @32K.

__global__ __launch_bounds__(NT) void mha_roles(
    const float* __restrict__ x,
    const float* __restrict__ wv,
    const float* __restrict__ bv,
    const float* __restrict__ fcw,
    const float* __restrict__ fcb,
    const float* __restrict__ g,
    const float* __restrict__ beta,
    float* __restrict__ out,
    float* __restrict__ xs,       // ws, poison-seeded (~0), atomic target
    float* __restrict__ u,        // ws, poison-seeded (~0), atomic target
    int* __restrict__ bar)        // ws, poison counters
{
    __shared__ float smem[33056];   // 129.1 KB -> exactly 1 block/CU

    const int tid  = threadIdx.x;
    const int bi   = blockIdx.x;
    const int lane = tid & 63;
    const int wid  = tid >> 6;

    int* xs_cnt = bar;        // counter line 0
    int* u_cnt  = bar + 64;   // counter line +256 B

    if (bi < NW) {
        // ========================= W-role =========================
        const int j  = bi;
        const int c0 = j * 32;
        float* wv_s  = smem;            // [512][32]  64 KB
        float* fcw_s = smem + 16384;    // [32][512]  64 KB
        float* T_s   = smem + 32768;    // [256]      (b,c) -> T
        float* bv_s  = smem + 33024;    // [32]

        // ---- stage weights NOW (overlaps x-read + xs wait) ----
        // 8 float4/thread, short-lived regs only (R11 lesson).
        float4 wb[4], fb[4];
#pragma unroll
        for (int i = 0; i < 4; ++i) {
            const int f = tid + i * 1024;         // float4 index 0..4095
            const int k = f >> 3, cg = f & 7;     // row, 16B col-group
            wb[i] = *(const float4*)(wv + (size_t)k * HDIM + c0 + cg * 4);
        }
#pragma unroll
        for (int i = 0; i < 4; ++i) {
            const int f = tid + i * 1024;         // fcw chunk is contiguous
            fb[i] = *(const float4*)(fcw + (size_t)c0 * DD + (size_t)f * 4);
        }
#pragma unroll
        for (int i = 0; i < 4; ++i)
            *(float4*)(wv_s + (size_t)(tid + i * 1024) * 4) = wb[i];
#pragma unroll
        for (int i = 0; i < 4; ++i)
            *(float4*)(fcw_s + (size_t)(tid + i * 1024) * 4) = fb[i];
        if (tid < 32) bv_s[tid] = bv[c0 + tid];

        // ---- wait for xs (128 X arrivals); staging drains at the barrier ----
        if (tid == 0) {
            while (__hip_atomic_load(xs_cnt, __ATOMIC_RELAXED,
                                     __HIP_MEMORY_SCOPE_AGENT) !=
                   POISON_I + 128)
                __builtin_amdgcn_s_sleep(1);
            asm volatile("" ::: "memory");
        }
        __syncthreads();

        // ---- T[b,c] = xs[b]·wv[:,c] + 1024*bv[c]  (quad-split over k) ----
        const int p = tid >> 2;          // 0..255 : b = p>>5, c = p&31
        const int q = tid & 3;           // k-quarter
        const int b = p >> 5, c = p & 31;
        const float* xrow = xs + b * DD + q * 128;   // first touch post-bar
        float t = 0.f;
#pragma unroll 8
        for (int i = 0; i < 128; ++i)
            t += xrow[i] * wv_s[(q * 128 + i) * 32 + c];
        t += __shfl_xor(t, 1, 64);
        t += __shfl_xor(t, 2, 64);
        if (q == 0) T_s[p] = t + 1024.f * bv_s[c];
        __syncthreads();

        // ---- u partials: u[b,d] += sum_{c local} T[b,c]*fcw[c,d] ----
        const int d = tid & 511;
        const int h = tid >> 9;          // c-half
        float acc[8] = {0.f, 0.f, 0.f, 0.f, 0.f, 0.f, 0.f, 0.f};
#pragma unroll
        for (int cc = 0; cc < 16; ++cc) {
            const int lc = h * 16 + cc;
            const float fw = fcw_s[lc * 512 + d];
#pragma unroll
            for (int b2 = 0; b2 < 8; ++b2)
                acc[b2] += T_s[b2 * 32 + lc] * fw;
        }
        float* ured = smem;              // reuse wv_s area (reads done)
        if (h == 1) {
#pragma unroll
            for (int b2 = 0; b2 < 8; ++b2) ured[b2 * 512 + d] = acc[b2];
        }
        __syncthreads();
        if (h == 0) {
#pragma unroll
            for (int b2 = 0; b2 < 8; ++b2)
                atomicAdd(&u[b2 * DD + d], acc[b2] + ured[b2 * 512 + d]);
        }

        // ---- arrive u_cnt (proven pattern: drain -> barrier -> add) ----
        asm volatile("s_waitcnt vmcnt(0)" ::: "memory");
        __syncthreads();
        if (tid == 0)
            __hip_atomic_fetch_add(u_cnt, 1, __ATOMIC_RELAXED,
                                   __HIP_MEMORY_SCOPE_AGENT);
    } else {
        // ========================= X-role =========================
        const int xb = bi - NW;          // 0..127
        const int b  = xb >> 4;          // batch
        const int s  = xb & 15;          // 64-row slice
        const int r0 = b * 1024 + s * 64;
        float* redA = smem;              // [8][512] 16 KB
        float* uf   = smem + 4096;       // [512]

        // ---- phase A: column-partials of my 64 rows ----
        float va[8] = {0.f, 0.f, 0.f, 0.f, 0.f, 0.f, 0.f, 0.f};
        const float* rbase = x + (size_t)(r0 + wid) * DD + lane * 8;
#pragma unroll
        for (int it = 0; it < 4; ++it) {
            float4 p0 = *(const float4*)(rbase + (size_t)it * 16 * DD);
            float4 p1 = *(const float4*)(rbase + (size_t)it * 16 * DD + 4);
            va[0] += p0.x; va[1] += p0.y; va[2] += p0.z; va[3] += p0.w;
            va[4] += p1.x; va[5] += p1.y; va[6] += p1.z; va[7] += p1.w;
        }
        if (wid < 8) {
#pragma unroll
            for (int i = 0; i < 8; ++i) redA[wid * 512 + lane * 8 + i] = va[i];
        }
        __syncthreads();
        if (wid >= 8) {
#pragma unroll
            for (int i = 0; i < 8; ++i)
                redA[(wid - 8) * 512 + lane * 8 + i] += va[i];
        }
        __syncthreads();
        if (tid < 512) {
            float ssum = 0.f;
#pragma unroll
            for (int gg = 0; gg < 8; ++gg) ssum += redA[gg * 512 + tid];
            atomicAdd(&xs[b * DD + tid], ssum);   // 16-way contention
        }

        // ---- arrive xs_cnt ----
        asm volatile("s_waitcnt vmcnt(0)" ::: "memory");
        __syncthreads();
        if (tid == 0)
            __hip_atomic_fetch_add(xs_cnt, 1, __ATOMIC_RELAXED,
                                   __HIP_MEMORY_SCOPE_AGENT);

        // prefetch LN constants during the wait (16 regs, short window)
        float4 g0  = *(const float4*)(g + lane * 8);
        float4 g1  = *(const float4*)(g + lane * 8 + 4);
        float4 bt0 = *(const float4*)(beta + lane * 8);
        float4 bt1 = *(const float4*)(beta + lane * 8 + 4);

        // ---- wait for u (128 W arrivals) ----
        if (tid == 0) {
            while (__hip_atomic_load(u_cnt, __ATOMIC_RELAXED,
                                     __HIP_MEMORY_SCOPE_AGENT) !=
                   POISON_I + 128)
                __builtin_amdgcn_s_sleep(1);
            asm volatile("" ::: "memory");
        }
        __syncthreads();

        if (tid < 512) uf[tid] = u[b * DD + tid] + fcb[tid];  // first touch
        __syncthreads();

        // ---- phase C: LN over my 64 rows; x re-read from L3 ----
        float4 uq0 = *(const float4*)(uf + lane * 8);
        float4 uq1 = *(const float4*)(uf + lane * 8 + 4);
#pragma unroll
        for (int it = 0; it < 4; ++it) {
            const size_t off = (size_t)(r0 + wid + it * 16) * DD + lane * 8;
            float4 x0 = *(const float4*)(x + off);
            float4 x1 = *(const float4*)(x + off + 4);

            float y[8];
            y[0] = x0.x + uq0.x;  y[1] = x0.y + uq0.y;
            y[2] = x0.z + uq0.z;  y[3] = x0.w + uq0.w;
            y[4] = x1.x + uq1.x;  y[5] = x1.y + uq1.y;
            y[6] = x1.z + uq1.z;  y[7] = x1.w + uq1.w;

            float s1 = 0.f, ss = 0.f;
#pragma unroll
            for (int i = 0; i < 8; ++i) { s1 += y[i]; ss += y[i] * y[i]; }
#pragma unroll
            for (int m = 1; m < 64; m <<= 1) {
                s1 += __shfl_xor(s1, m, 64);
                ss += __shfl_xor(ss, m, 64);
            }
            const float mean = s1 * (1.f / 512.f);
            const float var  = ss * (1.f / 512.f) - mean * mean;
            const float rstd = rsqrtf(var + EPS_LN);

            float4 o0, o1;
            o0.x = (y[0] - mean) * rstd * g0.x + bt0.x;
            o0.y = (y[1] - mean) * rstd * g0.y + bt0.y;
            o0.z = (y[2] - mean) * rstd * g0.z + bt0.z;
            o0.w = (y[3] - mean) * rstd * g0.w + bt0.w;
            o1.x = (y[4] - mean) * rstd * g1.x + bt1.x;
            o1.y = (y[5] - mean) * rstd * g1.y + bt1.y;
            o1.z = (y[6] - mean) * rstd * g1.z + bt1.z;
            o1.w = (y[7] - mean) * rstd * g1.w + bt1.w;
            *(float4*)(out + off)     = o0;
            *(float4*)(out + off + 4) = o1;
        }
    }
}

extern "C" void kernel_launch(void* const* d_in, const int* in_sizes, int n_in,
                              void* d_out, int out_size, void* d_ws, size_t ws_size,
                              hipStream_t stream) {
    // setup_inputs order:
    // 0 input, 1 wq, 2 bq, 3 wk, 4 bk, 5 wv, 6 bv, 7 score_w, 8 score_b,
    // 9 fc_w, 10 fc_b, 11 ln_g, 12 ln_b
    // (wq/bq/wk/bk/score_* are dead: softmax over a size-1 axis == 1.)
    const float* x   = (const float*)d_in[0];
    const float* wv  = (const float*)d_in[5];
    const float* bv  = (const float*)d_in[6];
    const float* fcw = (const float*)d_in[9];
    const float* fcb = (const float*)d_in[10];
    const float* lng = (const float*)d_in[11];
    const float* lnb = (const float*)d_in[12];

    float* xs  = (float*)d_ws;                      // 16 KB @ 0
    int*   bar = (int*)((char*)d_ws + 16 * 1024);   // counters
    float* u   = (float*)((char*)d_ws + 32 * 1024); // 16 KB
    float* out = (float*)d_out;

    mha_roles<<<NBLK, NT, 0, stream>>>(x, wv, bv, fcw, fcb, lng, lnb,
                                       out, xs, u, bar);
}

// Round 5
// 126.800 us; speedup vs baseline: 1.0869x; 1.0869x over previous
//
#include <hip/hip_runtime.h>

#define BB 8
#define LL 1024
#define DD 512
#define HDIM 4096
#define EPS_LN 1e-5f
#define NB 512
#define NT 512
#define POISON_I ((int)0xAAAAAAAAu)
#define ARRIVALS 64

// R14: R11 WITHOUT the spill — clean test of cohort pipelining.
//
// Evidence trail:
//  R9  (256x1024, 1 cohort/CU):        interior ~31 us   <- best
//  R10 (3 kernels, no sync):           ~34  -> sync is ~free
//  R11 (512x512 + wpre[48] prefetch):  ~46  -> launch_bounds(512,4) capped
//       VGPR at 64, wpre SPILLED (WRITE_SIZE 37MB). Cohort lever never
//       actually tested — run was scratch-bound.
//  R12 (512x1024, 32 waves/CU):        ~40  -> more waves hurt
//  R13 (W/X role split):               ~46  -> half-GPU idle per phase,
//       hbm 0.9TB/s, VALU 4.7% -> pure serialization. Role split dead.
//
// R14 = R11's exact passing phase code, minus wpre (wv streamed like R9),
// minus the min-waves launch-bounds cap. 512 blocks x 512 thr: 2 blocks/CU
// from DIFFERENT batch cohorts (bi>>6) -> when one cohort sits in a
// barrier/drain, the co-resident cohort's waves keep the HBM pipe and VALU
// fed. Per-thread live state ~45 VGPR (x segment 16 floats + temps) ->
// no spill without the cap. LDS 22.3 KB -> 2 blocks/CU guaranteed.
//
// Sync/poison: IDENTICAL proven pattern (vmcnt(0) drain -> relaxed
// agent-scope arrival -> thread-0 spin; xs/u written ONLY via device-scope
// atomicAdd; poison 0xAAAAAAAA == -3.03e-13f ~ 0; readers first-touch
// after count==POISON_I+64, control dep via __syncthreads).
//
// XCD locality: chunk j read by blocks {b*64+j, b=0..7}, all == j (mod 8)
// -> same XCD under round-robin. Performance-only assumption.
//
// Post-mortem sentinels: WRITE_SIZE ~16.05 MB, VGPR <= 64, no scratch.

__device__ __forceinline__ void batch_bar(int* cnt) {
    asm volatile("s_waitcnt vmcnt(0)" ::: "memory");  // every wave drains
    __syncthreads();
    if (threadIdx.x == 0) {
        __hip_atomic_fetch_add(cnt, 1, __ATOMIC_RELAXED,
                               __HIP_MEMORY_SCOPE_AGENT);
        while (__hip_atomic_load(cnt, __ATOMIC_RELAXED,
                                 __HIP_MEMORY_SCOPE_AGENT) !=
               POISON_I + ARRIVALS)
            __builtin_amdgcn_s_sleep(1);
        asm volatile("" ::: "memory");
    }
    __syncthreads();
}

__global__ __launch_bounds__(NT) void mha_fused(
    const float* __restrict__ x,
    const float* __restrict__ wv,
    const float* __restrict__ bv,
    const float* __restrict__ fcw,
    const float* __restrict__ fcb,
    const float* __restrict__ g,
    const float* __restrict__ beta,
    float* __restrict__ out,
    float* __restrict__ xs,       // ws, poison-seeded (~0), atomic target
    float* __restrict__ u,        // ws, poison-seeded (~0), atomic target
    int* __restrict__ bar)        // ws, 16 padded counter lines, poison
{
    __shared__ float redA[8][DD];    // 16 KB (phase A)
    __shared__ float xs_b[DD];       // 2 KB  (phase B)
    __shared__ float Tpart[8][64];   // 2 KB  (phase B)
    __shared__ float T_l[64];        // 256 B (phase B)
    __shared__ float uf[DD];         // 2 KB  (phase C)

    const int tid = threadIdx.x;
    const int bi  = blockIdx.x;      // 0..511
    const int b   = bi >> 6;         // batch
    const int j   = bi & 63;         // 16-row slice / 64-col chunk

    const int dv   = tid & 63;       // lane
    const int rowg = tid >> 6;       // wave id 0..7
    const int cI = dv;               // column within 64-col chunk
    const int kg = rowg;             // k-group (64 k's each)

    float4 xa0, xa1, xb0, xb1;       // x kept in regs A -> C

    // ---------------- Phase A: xs[b] += column-sums of my 16 rows ----------
    {
        const float* basep = x + ((size_t)(bi * 16 + rowg * 2)) * DD + dv * 8;
        xa0 = *(const float4*)(basep);
        xa1 = *(const float4*)(basep + 4);
        xb0 = *(const float4*)(basep + DD);
        xb1 = *(const float4*)(basep + DD + 4);

        float4* dst = (float4*)&redA[rowg][dv * 8];
        dst[0] = make_float4(xa0.x + xb0.x, xa0.y + xb0.y,
                             xa0.z + xb0.z, xa0.w + xb0.w);
        dst[1] = make_float4(xa1.x + xb1.x, xa1.y + xb1.y,
                             xa1.z + xb1.z, xa1.w + xb1.w);
        __syncthreads();

        float s = 0.f;                      // all 512 threads participate
#pragma unroll
        for (int gg = 0; gg < 8; ++gg) s += redA[gg][tid];
        atomicAdd(&xs[b * DD + tid], s);    // device-scope -> MALL
    }

    batch_bar(bar + b * 32);         // xs[b] complete (64 arrivals)

    // ---- Phase B: T[b, j*64..] from wv columns + u[b] partial via fcw ----
    {
        xs_b[tid] = xs[b * DD + tid];       // first touch after barrier
        __syncthreads();

        float t = 0.f;
        const float* wcol = wv + (size_t)(j * 64) + cI;
#pragma unroll 8
        for (int i = 0; i < 64; ++i) {
            const int k = kg * 64 + i;
            t += xs_b[k] * wcol[(size_t)k * HDIM];
        }
        Tpart[kg][cI] = t;
        __syncthreads();

        if (tid < 64) {
            float s = 0.f;
#pragma unroll
            for (int q = 0; q < 8; ++q) s += Tpart[q][tid];
            T_l[tid] = s + 1024.f * bv[j * 64 + tid];
        }
        __syncthreads();

        float a = 0.f;                      // u partial: all 512 threads
        const float* frow = fcw + (size_t)(j * 64) * DD + tid;
#pragma unroll 8
        for (int c = 0; c < 64; ++c)
            a += T_l[c] * frow[(size_t)c * DD];
        atomicAdd(&u[b * DD + tid], a);     // device-scope -> MALL
    }

    batch_bar(bar + (8 + b) * 32);   // u[b] complete (64 arrivals)

    // ---------- Phase C: y = LN(x + u + fc_b)*g + beta ----------
    {
        uf[tid] = u[b * DD + tid] + fcb[tid];   // first touch after barrier
        __syncthreads();

        float4 uq0 = *(const float4*)(uf + dv * 8);
        float4 uq1 = *(const float4*)(uf + dv * 8 + 4);
        float4 g0  = *(const float4*)(g + dv * 8);
        float4 g1  = *(const float4*)(g + dv * 8 + 4);
        float4 bt0 = *(const float4*)(beta + dv * 8);
        float4 bt1 = *(const float4*)(beta + dv * 8 + 4);

#pragma unroll
        for (int it = 0; it < 2; ++it) {
            const int row = bi * 16 + rowg * 2 + it;
            const size_t off = (size_t)row * DD + dv * 8;
            float4 x0 = (it == 0) ? xa0 : xb0;   // registers, no reload
            float4 x1 = (it == 0) ? xa1 : xb1;

            float y[8];
            y[0] = x0.x + uq0.x;  y[1] = x0.y + uq0.y;
            y[2] = x0.z + uq0.z;  y[3] = x0.w + uq0.w;
            y[4] = x1.x + uq1.x;  y[5] = x1.y + uq1.y;
            y[6] = x1.z + uq1.z;  y[7] = x1.w + uq1.w;

            float s1 = 0.f, ss = 0.f;
#pragma unroll
            for (int i = 0; i < 8; ++i) { s1 += y[i]; ss += y[i] * y[i]; }
#pragma unroll
            for (int m = 1; m < 64; m <<= 1) {
                s1 += __shfl_xor(s1, m, 64);
                ss += __shfl_xor(ss, m, 64);
            }
            const float mean = s1 * (1.f / 512.f);
            const float var  = ss * (1.f / 512.f) - mean * mean;
            const float rstd = rsqrtf(var + EPS_LN);

            float4 o0, o1;
            o0.x = (y[0] - mean) * rstd * g0.x + bt0.x;
            o0.y = (y[1] - mean) * rstd * g0.y + bt0.y;
            o0.z = (y[2] - mean) * rstd * g0.z + bt0.z;
            o0.w = (y[3] - mean) * rstd * g0.w + bt0.w;
            o1.x = (y[4] - mean) * rstd * g1.x + bt1.x;
            o1.y = (y[5] - mean) * rstd * g1.y + bt1.y;
            o1.z = (y[6] - mean) * rstd * g1.z + bt1.z;
            o1.w = (y[7] - mean) * rstd * g1.w + bt1.w;
            *(float4*)(out + off)     = o0;
            *(float4*)(out + off + 4) = o1;
        }
    }
}

extern "C" void kernel_launch(void* const* d_in, const int* in_sizes, int n_in,
                              void* d_out, int out_size, void* d_ws, size_t ws_size,
                              hipStream_t stream) {
    // setup_inputs order:
    // 0 input, 1 wq, 2 bq, 3 wk, 4 bk, 5 wv, 6 bv, 7 score_w, 8 score_b,
    // 9 fc_w, 10 fc_b, 11 ln_g, 12 ln_b
    // (wq/bq/wk/bk/score_* are dead: softmax over a size-1 axis == 1.)
    const float* x   = (const float*)d_in[0];
    const float* wv  = (const float*)d_in[5];
    const float* bv  = (const float*)d_in[6];
    const float* fcw = (const float*)d_in[9];
    const float* fcb = (const float*)d_in[10];
    const float* lng = (const float*)d_in[11];
    const float* lnb = (const float*)d_in[12];

    float* xs  = (float*)d_ws;                      // 16 KB @ 0
    int*   bar = (int*)((char*)d_ws + 16 * 1024);   // 16 counter lines
    float* u   = (float*)((char*)d_ws + 32 * 1024); // 16 KB final u
    float* out = (float*)d_out;

    mha_fused<<<NB, NT, 0, stream>>>(x, wv, bv, fcw, fcb, lng, lnb,
                                     out, xs, u, bar);
}